// Round 1
// baseline (37205.420 us; speedup 1.0000x reference)
//
#include <hip/hip_runtime.h>
#include <cstddef>
#include <cstdint>

// Problem dims (fixed)
#define T_   4096
#define IN_  1024
#define E_   512
#define G4_  2048   // 4*E

// ---------------------------------------------------------------------------
// Generic fp32 tiled GEMM: C[M,N] = A[M,K] @ op(B) (+ bias1[n] + bias2[n])
// BT=0: B is [K,N] row-major.  BT=1: B is [N,K] row-major (C = A @ B^T).
// Tile 128x128, K-chunk 16, 256 threads, 8x8 accum per thread.
// All dims must be multiples of 128/16 (true for every call here).
// ---------------------------------------------------------------------------
__global__ __launch_bounds__(256) void gemm_kernel(
    const float* __restrict__ A, const float* __restrict__ B, float* __restrict__ C,
    int M, int N, int K, int BT,
    const float* __restrict__ bias1, const float* __restrict__ bias2)
{
    __shared__ float As[16][128];
    __shared__ float Bs[16][132];   // +4 pad: breaks write bank conflicts, keeps 16B align
    const int tid = threadIdx.x;
    const int bm = blockIdx.y * 128;
    const int bn = blockIdx.x * 128;
    const int tx = tid & 15;        // n-dir
    const int ty = tid >> 4;        // m-dir
    const int lr = tid >> 1;        // loader row (A / B-transposed)
    const int lc = (tid & 1) * 8;   // loader k-offset
    const int bkk = tid & 15;       // loader k (B non-transposed)
    const int bn0 = (tid >> 4) * 8;

    float acc[8][8];
#pragma unroll
    for (int i = 0; i < 8; ++i)
#pragma unroll
        for (int j = 0; j < 8; ++j) acc[i][j] = 0.f;

    for (int k0 = 0; k0 < K; k0 += 16) {
        float av[8], bv[8];
        {
            const float* ap = A + (size_t)(bm + lr) * K + (k0 + lc);
            *(float4*)&av[0] = *(const float4*)ap;
            *(float4*)&av[4] = *(const float4*)(ap + 4);
        }
        if (BT) {
            const float* bp = B + (size_t)(bn + lr) * K + (k0 + lc);
            *(float4*)&bv[0] = *(const float4*)bp;
            *(float4*)&bv[4] = *(const float4*)(bp + 4);
        } else {
            const float* bp = B + (size_t)(k0 + bkk) * N + (bn + bn0);
            *(float4*)&bv[0] = *(const float4*)bp;
            *(float4*)&bv[4] = *(const float4*)(bp + 4);
        }
        __syncthreads();   // protect previous iteration's LDS reads
#pragma unroll
        for (int i = 0; i < 8; ++i) As[lc + i][lr] = av[i];
        if (BT) {
#pragma unroll
            for (int i = 0; i < 8; ++i) Bs[lc + i][lr] = bv[i];
        } else {
#pragma unroll
            for (int j = 0; j < 8; ++j) Bs[bkk][bn0 + j] = bv[j];
        }
        __syncthreads();
#pragma unroll
        for (int kk = 0; kk < 16; ++kk) {
            float a0[8], b0[8];
            *(float4*)&a0[0] = *(const float4*)&As[kk][ty * 8];
            *(float4*)&a0[4] = *(const float4*)&As[kk][ty * 8 + 4];
            *(float4*)&b0[0] = *(const float4*)&Bs[kk][tx * 8];
            *(float4*)&b0[4] = *(const float4*)&Bs[kk][tx * 8 + 4];
#pragma unroll
            for (int i = 0; i < 8; ++i)
#pragma unroll
                for (int j = 0; j < 8; ++j)
                    acc[i][j] = fmaf(a0[i], b0[j], acc[i][j]);
        }
    }

    float bias[8];
#pragma unroll
    for (int j = 0; j < 8; ++j) bias[j] = 0.f;
    if (bias1) {
#pragma unroll
        for (int j = 0; j < 8; ++j) bias[j] += bias1[bn + tx * 8 + j];
    }
    if (bias2) {
#pragma unroll
        for (int j = 0; j < 8; ++j) bias[j] += bias2[bn + tx * 8 + j];
    }
#pragma unroll
    for (int i = 0; i < 8; ++i) {
        float outv[8];
#pragma unroll
        for (int j = 0; j < 8; ++j) outv[j] = acc[i][j] + bias[j];
        float* cp = C + (size_t)(bm + ty * 8 + i) * N + (bn + tx * 8);
        *(float4*)cp = *(float4*)&outv[0];
        *(float4*)(cp + 4) = *(float4*)&outv[4];
    }
}

// ---------------------------------------------------------------------------
// Row softmax over 4096 columns, in place. One block (256 thr) per row,
// 16 elements/thread held in registers: one read + one write of the row.
// ---------------------------------------------------------------------------
__global__ __launch_bounds__(256) void softmax_kernel(float* __restrict__ S)
{
    __shared__ float red[8];
    float* p = S + (size_t)blockIdx.x * T_;
    const int tid = threadIdx.x;
    const int wid = tid >> 6;
    const int lane = tid & 63;
    float4 v[4];
#pragma unroll
    for (int i = 0; i < 4; ++i) v[i] = ((const float4*)p)[tid + 256 * i];
    float m = -3.0e38f;
#pragma unroll
    for (int i = 0; i < 4; ++i)
        m = fmaxf(m, fmaxf(fmaxf(v[i].x, v[i].y), fmaxf(v[i].z, v[i].w)));
#pragma unroll
    for (int o = 32; o; o >>= 1) m = fmaxf(m, __shfl_xor(m, o));
    if (lane == 0) red[wid] = m;
    __syncthreads();
    m = fmaxf(fmaxf(red[0], red[1]), fmaxf(red[2], red[3]));
    float s = 0.f;
#pragma unroll
    for (int i = 0; i < 4; ++i) {
        v[i].x = __expf(v[i].x - m); v[i].y = __expf(v[i].y - m);
        v[i].z = __expf(v[i].z - m); v[i].w = __expf(v[i].w - m);
        s += v[i].x + v[i].y + v[i].z + v[i].w;
    }
#pragma unroll
    for (int o = 32; o; o >>= 1) s += __shfl_xor(s, o);
    if (lane == 0) red[4 + wid] = s;
    __syncthreads();
    s = red[4] + red[5] + red[6] + red[7];
    const float inv = 1.f / s;
#pragma unroll
    for (int i = 0; i < 4; ++i) {
        v[i].x *= inv; v[i].y *= inv; v[i].z *= inv; v[i].w *= inv;
        ((float4*)p)[tid + 256 * i] = v[i];
    }
}

// u_mod = u * out_vec, elementwise over T*E floats (float4 vectorized)
__global__ __launch_bounds__(256) void umod_kernel(
    const float* __restrict__ u, const float* __restrict__ ov, float* __restrict__ um)
{
    const int i = blockIdx.x * 256 + threadIdx.x;
    float4 a = ((const float4*)u)[i];
    float4 b = ((const float4*)ov)[i];
    float4 c;
    c.x = a.x * b.x; c.y = a.y * b.y; c.z = a.z * b.z; c.w = a.w * b.w;
    ((float4*)um)[i] = c;
}

// zero the sync counters (ws is poisoned 0xAA before every launch)
__global__ void zero_kernel(unsigned int* __restrict__ p)
{
    p[threadIdx.x] = 0u;
}

// ---------------------------------------------------------------------------
// Persistent bidirectional LSTM.
// Grid = 256 blocks: dir = blockIdx.x>>7 (0=fwd,1=bwd), w = blockIdx.x&127.
// Each WG owns HS=4 hidden units -> RPW=16 gate rows of W_hh, staged in LDS
// (fp32, row stride 513 to break bank conflicts). Gate inputs Xg = u_mod@W_ih^T
// + biases are precomputed by gemm_kernel; prefetched one step ahead.
// Per step: h_{t-1} is read from an L3-coherent global buffer (agent-scope
// atomics; parity double-buffered), matvec from LDS, gates, own h-slice is
// published, then a monotonic per-direction counter barrier.
// ---------------------------------------------------------------------------
#define NW_  128   // workgroups per direction
#define RPW_ 16    // gate rows per WG (2048/128)
#define HS_  4     // hidden units per WG (512/128)

__global__ __launch_bounds__(256) void lstm_kernel(
    const float* __restrict__ whh_f, const float* __restrict__ whh_b,
    const float* __restrict__ xg_f, const float* __restrict__ xg_b,
    float* __restrict__ hf_out, float* __restrict__ hb_out,
    float* __restrict__ hbuf,          // [2 dirs][2 parity][512]
    unsigned int* __restrict__ cnt)    // [2 dirs] at stride 64 uints
{
    __shared__ float sw[RPW_ * 513];   // 32,832 B
    __shared__ float sh[E_];
    __shared__ float sred[16 * RPW_];
    __shared__ float sgate[RPW_];
    __shared__ float sxg[RPW_];
    __shared__ float sc[HS_];

    const int tid = threadIdx.x;
    const int dir = blockIdx.x >> 7;
    const int w = blockIdx.x & 127;
    const int hbase = w * HS_;

    const float* whh = dir ? whh_b : whh_f;
    const float* xg  = dir ? xg_b : xg_f;
    float* hout = dir ? hb_out : hf_out;
    float* myh = hbuf + dir * 2 * E_;
    unsigned int* myc = cnt + dir * 64;

    // Stage this WG's 16 gate rows of W_hh into LDS (one-time).
    for (int i = tid; i < RPW_ * E_; i += 256) {
        const int r = i >> 9;          // local row 0..15
        const int k = i & 511;
        const int g = r >> 2, j = r & 3;
        sw[r * 513 + k] = whh[(size_t)(g * E_ + hbase + j) * E_ + k];
    }
    if (tid < HS_) sc[tid] = 0.f;
    __syncthreads();

    const int row = tid & 15;          // local gate row
    const int cch = tid >> 4;          // k-chunk 0..15 (32 k each)

    // prefetch Xg for first step
    float xgv = 0.f;
    {
        const int t0 = dir ? (T_ - 1) : 0;
        if (tid < RPW_) {
            const int g = tid >> 2, j = tid & 3;
            xgv = xg[(size_t)t0 * G4_ + g * E_ + hbase + j];
        }
    }

    unsigned int budget = 1u << 23;    // spin safety valve (never hit when healthy)

    for (int s = 0; s < T_; ++s) {
        const int t = dir ? (T_ - 1 - s) : s;

        if (s > 0) {
            const unsigned int target = (unsigned int)(NW_ * s);
            if (tid == 0) {
                while (budget &&
                       __hip_atomic_load(myc, __ATOMIC_ACQUIRE, __HIP_MEMORY_SCOPE_AGENT) < target) {
                    --budget;
                }
            }
            __syncthreads();
            const unsigned int* src = (const unsigned int*)(myh + ((s - 1) & 1) * E_);
            for (int i = tid; i < E_; i += 256)
                sh[i] = __uint_as_float(
                    __hip_atomic_load(src + i, __ATOMIC_RELAXED, __HIP_MEMORY_SCOPE_AGENT));
        } else {
            for (int i = tid; i < E_; i += 256) sh[i] = 0.f;
        }
        if (tid < RPW_) sxg[tid] = xgv;
        __syncthreads();

        // matvec partial: 32 fp32 FMAs per thread from LDS
        {
            const float* wr = &sw[row * 513 + (cch << 5)];
            const float* hv = &sh[cch << 5];
            float sum = 0.f;
#pragma unroll
            for (int k = 0; k < 32; ++k) sum = fmaf(wr[k], hv[k], sum);
            sred[(cch << 4) + row] = sum;
        }
        __syncthreads();

        if (tid < RPW_) {
            float g = sxg[tid];
#pragma unroll
            for (int c = 0; c < 16; ++c) g += sred[(c << 4) + tid];
            sgate[tid] = ((tid >> 2) == 2) ? tanhf(g)
                                           : 1.f / (1.f + __expf(-g));
        }
        __syncthreads();

        if (tid < HS_) {
            const float iv = sgate[tid], fv = sgate[4 + tid],
                        gv = sgate[8 + tid], ov = sgate[12 + tid];
            const float c = fv * sc[tid] + iv * gv;
            sc[tid] = c;
            const float h = ov * tanhf(c);
            unsigned int* dst = (unsigned int*)(myh + (s & 1) * E_) + hbase + tid;
            __hip_atomic_store(dst, __float_as_uint(h),
                               __ATOMIC_RELAXED, __HIP_MEMORY_SCOPE_AGENT);
            hout[(size_t)t * E_ + hbase + tid] = h;
        }
        __syncthreads();   // drains the h stores of all waves before the arrive
        if (tid == 0)
            __hip_atomic_fetch_add(myc, 1u, __ATOMIC_RELEASE, __HIP_MEMORY_SCOPE_AGENT);

        // prefetch next step's Xg while (others) spin
        if (s + 1 < T_ && tid < RPW_) {
            const int tn = dir ? (T_ - 2 - s) : (s + 1);
            const int g = tid >> 2, j = tid & 3;
            xgv = xg[(size_t)tn * G4_ + g * E_ + hbase + j];
        }
    }
}

// score[t] = dot(hf[t], fw[0:512]) + dot(hb[t], fw[512:1024]) + fb
// one wave per t; 4 t per block.
__global__ __launch_bounds__(256) void final_kernel(
    const float* __restrict__ hf, const float* __restrict__ hb,
    const float* __restrict__ fw, const float* __restrict__ fb,
    float* __restrict__ out)
{
    const int t = blockIdx.x * 4 + (threadIdx.x >> 6);
    const int lane = threadIdx.x & 63;
    float s = 0.f;
#pragma unroll
    for (int i = 0; i < 8; ++i) {
        const int e = lane + 64 * i;
        s += hf[(size_t)t * E_ + e] * fw[e];
    }
#pragma unroll
    for (int i = 0; i < 8; ++i) {
        const int e = lane + 64 * i;
        s += hb[(size_t)t * E_ + e] * fw[E_ + e];
    }
#pragma unroll
    for (int o = 32; o; o >>= 1) s += __shfl_xor(s, o);
    if (lane == 0) out[t] = s + fb[0];
}

// ---------------------------------------------------------------------------
// Workspace layout (floats; 1 MB = 262144 floats). Peak ~96 MB via overlays:
//   a  [0,8MB)  b [8,16)  u [16,24)  S [24,88)  ov [88,96)
//   um [24,32)  (overlays dead S head)
//   xf [32,64)  xb [64,96)  (overlay dead S tail / ov)
//   hf [0,8)    hb [8,16)   (overlay dead a/b)
//   hbuf @96MB (2048 floats), cnt after it (128 uints)
// ---------------------------------------------------------------------------
extern "C" void kernel_launch(void* const* d_in, const int* in_sizes, int n_in,
                              void* d_out, int out_size, void* d_ws, size_t ws_size,
                              hipStream_t stream)
{
    const float* x     = (const float*)d_in[0];
    const float* Amat  = (const float*)d_in[1];
    const float* Bmat  = (const float*)d_in[2];
    const float* Umat  = (const float*)d_in[3];
    const float* wih_f = (const float*)d_in[4];
    const float* whh_f = (const float*)d_in[5];
    const float* bih_f = (const float*)d_in[6];
    const float* bhh_f = (const float*)d_in[7];
    const float* wih_b = (const float*)d_in[8];
    const float* whh_b = (const float*)d_in[9];
    const float* bih_b = (const float*)d_in[10];
    const float* bhh_b = (const float*)d_in[11];
    const float* fw    = (const float*)d_in[12];
    const float* fb    = (const float*)d_in[13];
    float* out = (float*)d_out;
    float* ws = (float*)d_ws;

    const size_t MBf = 262144;  // floats per MB
    float* a_  = ws;
    float* b_  = ws + 8 * MBf;
    float* u_  = ws + 16 * MBf;
    float* S_  = ws + 24 * MBf;
    float* ov_ = ws + 88 * MBf;
    float* um_ = ws + 24 * MBf;   // overlays S (dead by then)
    float* xf_ = ws + 32 * MBf;
    float* xb_ = ws + 64 * MBf;
    float* hf_ = ws;              // overlays a (dead)
    float* hb_ = ws + 8 * MBf;    // overlays b (dead)
    float* hbuf_ = ws + 96 * MBf;
    unsigned int* cnt_ = (unsigned int*)(ws + 96 * MBf + 2048);

    dim3 blk(256);

    // a, b, u = x @ {A,B,U}   [4096x1024]x[1024x512]
    gemm_kernel<<<dim3(4, 32), blk, 0, stream>>>(x, Amat, a_, T_, E_, IN_, 0, nullptr, nullptr);
    gemm_kernel<<<dim3(4, 32), blk, 0, stream>>>(x, Bmat, b_, T_, E_, IN_, 0, nullptr, nullptr);
    gemm_kernel<<<dim3(4, 32), blk, 0, stream>>>(x, Umat, u_, T_, E_, IN_, 0, nullptr, nullptr);
    // S = u @ a^T  [4096x4096]
    gemm_kernel<<<dim3(32, 32), blk, 0, stream>>>(u_, a_, S_, T_, T_, E_, 1, nullptr, nullptr);
    softmax_kernel<<<dim3(T_), blk, 0, stream>>>(S_);
    // out_vec = P @ b
    gemm_kernel<<<dim3(4, 32), blk, 0, stream>>>(S_, b_, ov_, T_, E_, T_, 0, nullptr, nullptr);
    umod_kernel<<<dim3(2048), blk, 0, stream>>>(u_, ov_, um_);
    // Xg = u_mod @ w_ih^T + (b_ih + b_hh)
    gemm_kernel<<<dim3(16, 32), blk, 0, stream>>>(um_, wih_f, xf_, T_, G4_, E_, 1, bih_f, bhh_f);
    gemm_kernel<<<dim3(16, 32), blk, 0, stream>>>(um_, wih_b, xb_, T_, G4_, E_, 1, bih_b, bhh_b);
    // sequential recurrence
    zero_kernel<<<dim3(1), dim3(128), 0, stream>>>(cnt_);
    lstm_kernel<<<dim3(256), blk, 0, stream>>>(whh_f, whh_b, xf_, xb_, hf_, hb_, hbuf_, cnt_);
    // projection
    final_kernel<<<dim3(1024), blk, 0, stream>>>(hf_, hb_, fw, fb, out);
}

// Round 2
// 13879.094 us; speedup vs baseline: 2.6807x; 2.6807x over previous
//
#include <hip/hip_runtime.h>
#include <cstddef>
#include <cstdint>

// Problem dims (fixed)
#define T_   4096
#define IN_  1024
#define E_   512
#define G4_  2048   // 4*E

// ---------------------------------------------------------------------------
// Generic fp32 tiled GEMM: C[M,N] = A[M,K] @ op(B) (+ bias1[n] + bias2[n])
// BT=0: B is [K,N] row-major.  BT=1: B is [N,K] row-major (C = A @ B^T).
// Tile 128x128, K-chunk 16, 256 threads, 8x8 accum per thread.
// ---------------------------------------------------------------------------
__global__ __launch_bounds__(256) void gemm_kernel(
    const float* __restrict__ A, const float* __restrict__ B, float* __restrict__ C,
    int M, int N, int K, int BT,
    const float* __restrict__ bias1, const float* __restrict__ bias2)
{
    __shared__ float As[16][128];
    __shared__ float Bs[16][132];
    const int tid = threadIdx.x;
    const int bm = blockIdx.y * 128;
    const int bn = blockIdx.x * 128;
    const int tx = tid & 15;
    const int ty = tid >> 4;
    const int lr = tid >> 1;
    const int lc = (tid & 1) * 8;
    const int bkk = tid & 15;
    const int bn0 = (tid >> 4) * 8;

    float acc[8][8];
#pragma unroll
    for (int i = 0; i < 8; ++i)
#pragma unroll
        for (int j = 0; j < 8; ++j) acc[i][j] = 0.f;

    for (int k0 = 0; k0 < K; k0 += 16) {
        float av[8], bv[8];
        {
            const float* ap = A + (size_t)(bm + lr) * K + (k0 + lc);
            *(float4*)&av[0] = *(const float4*)ap;
            *(float4*)&av[4] = *(const float4*)(ap + 4);
        }
        if (BT) {
            const float* bp = B + (size_t)(bn + lr) * K + (k0 + lc);
            *(float4*)&bv[0] = *(const float4*)bp;
            *(float4*)&bv[4] = *(const float4*)(bp + 4);
        } else {
            const float* bp = B + (size_t)(k0 + bkk) * N + (bn + bn0);
            *(float4*)&bv[0] = *(const float4*)bp;
            *(float4*)&bv[4] = *(const float4*)(bp + 4);
        }
        __syncthreads();
#pragma unroll
        for (int i = 0; i < 8; ++i) As[lc + i][lr] = av[i];
        if (BT) {
#pragma unroll
            for (int i = 0; i < 8; ++i) Bs[lc + i][lr] = bv[i];
        } else {
#pragma unroll
            for (int j = 0; j < 8; ++j) Bs[bkk][bn0 + j] = bv[j];
        }
        __syncthreads();
#pragma unroll
        for (int kk = 0; kk < 16; ++kk) {
            float a0[8], b0[8];
            *(float4*)&a0[0] = *(const float4*)&As[kk][ty * 8];
            *(float4*)&a0[4] = *(const float4*)&As[kk][ty * 8 + 4];
            *(float4*)&b0[0] = *(const float4*)&Bs[kk][tx * 8];
            *(float4*)&b0[4] = *(const float4*)&Bs[kk][tx * 8 + 4];
#pragma unroll
            for (int i = 0; i < 8; ++i)
#pragma unroll
                for (int j = 0; j < 8; ++j)
                    acc[i][j] = fmaf(a0[i], b0[j], acc[i][j]);
        }
    }

    float bias[8];
#pragma unroll
    for (int j = 0; j < 8; ++j) bias[j] = 0.f;
    if (bias1) {
#pragma unroll
        for (int j = 0; j < 8; ++j) bias[j] += bias1[bn + tx * 8 + j];
    }
    if (bias2) {
#pragma unroll
        for (int j = 0; j < 8; ++j) bias[j] += bias2[bn + tx * 8 + j];
    }
#pragma unroll
    for (int i = 0; i < 8; ++i) {
        float outv[8];
#pragma unroll
        for (int j = 0; j < 8; ++j) outv[j] = acc[i][j] + bias[j];
        float* cp = C + (size_t)(bm + ty * 8 + i) * N + (bn + tx * 8);
        *(float4*)cp = *(float4*)&outv[0];
        *(float4*)(cp + 4) = *(float4*)&outv[4];
    }
}

// ---------------------------------------------------------------------------
// Row softmax over 4096 columns, in place. One block per row.
// ---------------------------------------------------------------------------
__global__ __launch_bounds__(256) void softmax_kernel(float* __restrict__ S)
{
    __shared__ float red[8];
    float* p = S + (size_t)blockIdx.x * T_;
    const int tid = threadIdx.x;
    const int wid = tid >> 6;
    const int lane = tid & 63;
    float4 v[4];
#pragma unroll
    for (int i = 0; i < 4; ++i) v[i] = ((const float4*)p)[tid + 256 * i];
    float m = -3.0e38f;
#pragma unroll
    for (int i = 0; i < 4; ++i)
        m = fmaxf(m, fmaxf(fmaxf(v[i].x, v[i].y), fmaxf(v[i].z, v[i].w)));
#pragma unroll
    for (int o = 32; o; o >>= 1) m = fmaxf(m, __shfl_xor(m, o));
    if (lane == 0) red[wid] = m;
    __syncthreads();
    m = fmaxf(fmaxf(red[0], red[1]), fmaxf(red[2], red[3]));
    float s = 0.f;
#pragma unroll
    for (int i = 0; i < 4; ++i) {
        v[i].x = __expf(v[i].x - m); v[i].y = __expf(v[i].y - m);
        v[i].z = __expf(v[i].z - m); v[i].w = __expf(v[i].w - m);
        s += v[i].x + v[i].y + v[i].z + v[i].w;
    }
#pragma unroll
    for (int o = 32; o; o >>= 1) s += __shfl_xor(s, o);
    if (lane == 0) red[4 + wid] = s;
    __syncthreads();
    s = red[4] + red[5] + red[6] + red[7];
    const float inv = 1.f / s;
#pragma unroll
    for (int i = 0; i < 4; ++i) {
        v[i].x *= inv; v[i].y *= inv; v[i].z *= inv; v[i].w *= inv;
        ((float4*)p)[tid + 256 * i] = v[i];
    }
}

// u_mod = u * out_vec, elementwise
__global__ __launch_bounds__(256) void umod_kernel(
    const float* __restrict__ u, const float* __restrict__ ov, float* __restrict__ um)
{
    const int i = blockIdx.x * 256 + threadIdx.x;
    float4 a = ((const float4*)u)[i];
    float4 b = ((const float4*)ov)[i];
    float4 c;
    c.x = a.x * b.x; c.y = a.y * b.y; c.z = a.z * b.z; c.w = a.w * b.w;
    ((float4*)um)[i] = c;
}

// ---------------------------------------------------------------------------
// Persistent bidirectional LSTM, v2: tagged-h dataflow sync (no counters,
// no atomic RMW, no release fences). 256 WGs: dir = blockIdx>>7, w = &127.
// WG owns 4 hidden units; wave `wid` owns unit u = 4w+wid (all 4 gate rows).
// Per step: poll 512 tagged 8B slots (2/thread) -> stage h into LDS ->
// ONE __syncthreads -> b128 LDS matvec -> shfl-reduce -> gates in-wave ->
// lane0 publishes (tag|h) with a single relaxed agent-scope 8B atomic store.
// Proof sketch: WG at step s implies all WGs completed step s-1, hence all
// finished their step-(s-1) polls -> overwriting the (s-2)-tagged slot of the
// same parity is safe -> 2 parity buffers suffice; exact tag match means
// stale tags (incl. 0xAAAAAAAA poison) can never false-trigger.
// W_hh rows stored as 16 chunks of 32 floats at stride 36 (b128-aligned,
// h reads broadcast across gate lanes -> near-conflict-free).
// ---------------------------------------------------------------------------
__global__ __launch_bounds__(256) void lstm_kernel(
    const float* __restrict__ whh_f, const float* __restrict__ whh_b,
    const float* __restrict__ xg_f, const float* __restrict__ xg_b,
    float* __restrict__ hf_out, float* __restrict__ hb_out,
    unsigned long long* __restrict__ hbuf)   // [2 dirs][2 parity][512] tagged
{
    __shared__ float sw[16 * 576];     // 36,864 B  (16 rows x 16 chunks x 36)
    __shared__ float sh[2][16 * 36];   //  4,608 B  (double-buffered staged h)

    const int tid  = threadIdx.x;
    const int dir  = blockIdx.x >> 7;
    const int w    = blockIdx.x & 127;
    const int wid  = tid >> 6;          // unit-in-WG 0..3
    const int lane = tid & 63;
    const int g    = lane >> 4;         // gate 0..3 (i,f,g,o)
    const int c    = lane & 15;         // k-chunk 0..15 (32 elems each)
    const int u    = w * 4 + wid;       // global hidden unit 0..511

    const float* whh = dir ? whh_b : whh_f;
    const float* xg  = dir ? xg_b  : xg_f;
    float* hout = dir ? hb_out : hf_out;
    unsigned long long* hb = hbuf + dir * 1024;

    // One-time stage of this WG's 16 gate rows, chunk-padded layout.
    for (int i = tid; i < 16 * 512; i += 256) {
        const int r = i >> 9;          // local row: r = jj*4 + gg
        const int k = i & 511;
        const int gg = r & 3, jj = r >> 2;
        sw[r * 576 + (k >> 5) * 36 + (k & 31)] =
            whh[(size_t)(gg * E_ + w * 4 + jj) * E_ + k];
    }
    for (int i = tid; i < 16 * 36; i += 256) sh[0][i] = 0.f;  // h_init = 0

    const float* wrow = &sw[(wid * 4 + g) * 576 + c * 36];
    float creg = 0.f;
    float xv = xg[(size_t)(dir ? (T_ - 1) : 0) * G4_ + g * E_ + u];
    unsigned int budget = 1u << 23;    // hang-prevention only; never hit healthy

    const int e0 = 2 * tid, e1 = 2 * tid + 1;
    const int p0 = (e0 >> 5) * 36 + (e0 & 31);
    const int p1 = (e1 >> 5) * 36 + (e1 & 31);

    for (int s = 0; s < T_; ++s) {
        const int t = dir ? (T_ - 1 - s) : s;

        if (s > 0) {
            const unsigned int tg = (unsigned int)(s - 1);
            const unsigned long long* src = hb + ((s - 1) & 1) * 512;
            unsigned long long v0, v1;
            for (;;) {
                v0 = __hip_atomic_load(src + e0, __ATOMIC_RELAXED, __HIP_MEMORY_SCOPE_AGENT);
                if ((unsigned int)(v0 >> 32) == tg || !--budget) break;
            }
            for (;;) {
                v1 = __hip_atomic_load(src + e1, __ATOMIC_RELAXED, __HIP_MEMORY_SCOPE_AGENT);
                if ((unsigned int)(v1 >> 32) == tg || !--budget) break;
            }
            float* dst = sh[s & 1];
            dst[p0] = __uint_as_float((unsigned int)v0);
            dst[p1] = __uint_as_float((unsigned int)v1);
        }
        __syncthreads();   // the ONLY per-step barrier

        // matvec partial: 32 FMAs, both operands b128 from LDS
        const float* hrow = &sh[s & 1][c * 36];
        float sum = 0.f;
#pragma unroll
        for (int k = 0; k < 32; ++k) sum = fmaf(wrow[k], hrow[k], sum);

        // reduce across the 16 chunk-lanes of this gate group
        sum += __shfl_xor(sum, 1);
        sum += __shfl_xor(sum, 2);
        sum += __shfl_xor(sum, 4);
        sum += __shfl_xor(sum, 8);

        float val = sum + xv;
        val = (g == 2) ? tanhf(val) : 1.f / (1.f + __expf(-val));

        // gather the 4 gates of this unit (groups hold identical values)
        const float iv = __shfl(val, c);
        const float fv = __shfl(val, c + 16);
        const float gv = __shfl(val, c + 32);
        const float ov = __shfl(val, c + 48);
        creg = fv * creg + iv * gv;           // identical on all 64 lanes
        const float h = ov * tanhf(creg);

        if (lane == 0) {
            const unsigned long long pkt =
                ((unsigned long long)(unsigned int)s << 32) |
                (unsigned long long)__float_as_uint(h);
            __hip_atomic_store(hb + (s & 1) * 512 + u, pkt,
                               __ATOMIC_RELAXED, __HIP_MEMORY_SCOPE_AGENT);
            hout[(size_t)t * E_ + u] = h;
        }

        if (s + 1 < T_)
            xv = xg[(size_t)(dir ? (T_ - 2 - s) : (s + 1)) * G4_ + g * E_ + u];
    }
}

// score[t] = dot(hf[t], fw[0:512]) + dot(hb[t], fw[512:1024]) + fb
__global__ __launch_bounds__(256) void final_kernel(
    const float* __restrict__ hf, const float* __restrict__ hb,
    const float* __restrict__ fw, const float* __restrict__ fb,
    float* __restrict__ out)
{
    const int t = blockIdx.x * 4 + (threadIdx.x >> 6);
    const int lane = threadIdx.x & 63;
    float s = 0.f;
#pragma unroll
    for (int i = 0; i < 8; ++i) {
        const int e = lane + 64 * i;
        s += hf[(size_t)t * E_ + e] * fw[e];
    }
#pragma unroll
    for (int i = 0; i < 8; ++i) {
        const int e = lane + 64 * i;
        s += hb[(size_t)t * E_ + e] * fw[E_ + e];
    }
#pragma unroll
    for (int o = 32; o; o >>= 1) s += __shfl_xor(s, o);
    if (lane == 0) out[t] = s + fb[0];
}

// ---------------------------------------------------------------------------
// Workspace layout (floats; 1 MB = 262144 floats). Peak ~96 MB via overlays:
//   a [0,8MB) b [8,16) u [16,24) S [24,88) ov [88,96)
//   um [24,32)  xf [32,64)  xb [64,96)  hf [0,8)  hb [8,16)
//   tagged hbuf @96MB (2048 x 8B = 16KB)
// ---------------------------------------------------------------------------
extern "C" void kernel_launch(void* const* d_in, const int* in_sizes, int n_in,
                              void* d_out, int out_size, void* d_ws, size_t ws_size,
                              hipStream_t stream)
{
    const float* x     = (const float*)d_in[0];
    const float* Amat  = (const float*)d_in[1];
    const float* Bmat  = (const float*)d_in[2];
    const float* Umat  = (const float*)d_in[3];
    const float* wih_f = (const float*)d_in[4];
    const float* whh_f = (const float*)d_in[5];
    const float* bih_f = (const float*)d_in[6];
    const float* bhh_f = (const float*)d_in[7];
    const float* wih_b = (const float*)d_in[8];
    const float* whh_b = (const float*)d_in[9];
    const float* bih_b = (const float*)d_in[10];
    const float* bhh_b = (const float*)d_in[11];
    const float* fw    = (const float*)d_in[12];
    const float* fb    = (const float*)d_in[13];
    float* out = (float*)d_out;
    float* ws = (float*)d_ws;

    const size_t MBf = 262144;
    float* a_  = ws;
    float* b_  = ws + 8 * MBf;
    float* u_  = ws + 16 * MBf;
    float* S_  = ws + 24 * MBf;
    float* ov_ = ws + 88 * MBf;
    float* um_ = ws + 24 * MBf;
    float* xf_ = ws + 32 * MBf;
    float* xb_ = ws + 64 * MBf;
    float* hf_ = ws;
    float* hb_ = ws + 8 * MBf;
    unsigned long long* hbuf_ = (unsigned long long*)(ws + 96 * MBf);

    dim3 blk(256);

    gemm_kernel<<<dim3(4, 32), blk, 0, stream>>>(x, Amat, a_, T_, E_, IN_, 0, nullptr, nullptr);
    gemm_kernel<<<dim3(4, 32), blk, 0, stream>>>(x, Bmat, b_, T_, E_, IN_, 0, nullptr, nullptr);
    gemm_kernel<<<dim3(4, 32), blk, 0, stream>>>(x, Umat, u_, T_, E_, IN_, 0, nullptr, nullptr);
    gemm_kernel<<<dim3(32, 32), blk, 0, stream>>>(u_, a_, S_, T_, T_, E_, 1, nullptr, nullptr);
    softmax_kernel<<<dim3(T_), blk, 0, stream>>>(S_);
    gemm_kernel<<<dim3(4, 32), blk, 0, stream>>>(S_, b_, ov_, T_, E_, T_, 0, nullptr, nullptr);
    umod_kernel<<<dim3(2048), blk, 0, stream>>>(u_, ov_, um_);
    gemm_kernel<<<dim3(16, 32), blk, 0, stream>>>(um_, wih_f, xf_, T_, G4_, E_, 1, bih_f, bhh_f);
    gemm_kernel<<<dim3(16, 32), blk, 0, stream>>>(um_, wih_b, xb_, T_, G4_, E_, 1, bih_b, bhh_b);
    lstm_kernel<<<dim3(256), blk, 0, stream>>>(whh_f, whh_b, xf_, xb_, hf_, hb_, hbuf_);
    final_kernel<<<dim3(1024), blk, 0, stream>>>(hf_, hb_, fw, fb, out);
}